// Round 1
// baseline (293.475 us; speedup 1.0000x reference)
//
#include <hip/hip_runtime.h>
#include <hip/hip_bf16.h>
#include <cstdint>

#define NHEADS 16
#define HDIM   64
#define BATCH  2
#define SEQ    2048
#define DMODEL 1024
#define MROWS  (BATCH * SEQ)   // 4096

using bf16 = __hip_bfloat16;
typedef __attribute__((ext_vector_type(8))) short bf16x8;
typedef __attribute__((ext_vector_type(4))) float f32x4;

__device__ __forceinline__ void gload_lds16(const bf16* g, bf16* l) {
  __builtin_amdgcn_global_load_lds(
      (const __attribute__((address_space(1))) unsigned int*)g,
      (__attribute__((address_space(3))) unsigned int*)l, 16, 0, 0);
}

// ---------- cast X fp32 -> bf16 ----------
__global__ __launch_bounds__(256) void cast_x_kernel(const float* __restrict__ in,
                                                     bf16* __restrict__ out) {
  const int i = (blockIdx.x * 256 + threadIdx.x) * 4;
  const float4 v = *reinterpret_cast<const float4*>(in + i);
  __hip_bfloat162 p0 = __float22bfloat162_rn(make_float2(v.x, v.y));
  __hip_bfloat162 p1 = __float22bfloat162_rn(make_float2(v.z, v.w));
  reinterpret_cast<__hip_bfloat162*>(out + i)[0] = p0;
  reinterpret_cast<__hip_bfloat162*>(out + i)[1] = p1;
}

// ---------- transpose-cast W [K][N] fp32 -> Wt [N][K] bf16 ----------
__global__ __launch_bounds__(256) void wtrans_kernel(const float* __restrict__ W,
                                                     bf16* __restrict__ Wt) {
  __shared__ float tile[32][33];
  const int n0 = blockIdx.x * 32, k0 = blockIdx.y * 32;
  const int tx = threadIdx.x & 31, ty = threadIdx.x >> 5;  // 32 x 8
  #pragma unroll
  for (int r = 0; r < 32; r += 8)
    tile[ty + r][tx] = W[(size_t)(k0 + ty + r) * DMODEL + n0 + tx];
  __syncthreads();
  #pragma unroll
  for (int r = 0; r < 32; r += 8)
    Wt[(size_t)(n0 + ty + r) * DMODEL + k0 + tx] = __float2bfloat16(tile[tx][ty + r]);
}

// ---------- GEMM: C[M][N] = A[M][K] * Bt[N][K]^T ----------
// OUT_MODE 0: fused QKV epilogue (bf16, head-split Q/K, transposed V)
// OUT_MODE 1: fp32 out + bias
template <int OUT_MODE>
__global__ __launch_bounds__(256) void gemm_bt(const bf16* __restrict__ A,
                                               const bf16* __restrict__ Bt, int Kdim,
                                               bf16* __restrict__ q_out, bf16* __restrict__ k_out,
                                               bf16* __restrict__ v_out,
                                               float* __restrict__ f_out,
                                               const float* __restrict__ bias, int Ndim) {
  __shared__ __align__(16) bf16 As[128 * 32];
  __shared__ __align__(16) bf16 Bs[128 * 32];
  const int tid = threadIdx.x;
  const int lane = tid & 63, wave = tid >> 6;
  const int lr = lane & 15, lg = lane >> 4;
  const int brow = blockIdx.y * 128, bcol = blockIdx.x * 128;
  const int wr = (wave >> 1) * 64, wc = (wave & 1) * 64;
  f32x4 acc[4][4] = {};

  const int c0 = tid, c1 = 256 + tid;
  const int row0 = c0 >> 2, kc0 = (c0 & 3) * 8;
  const int row1 = c1 >> 2, kc1 = (c1 & 3) * 8;

  for (int k0 = 0; k0 < Kdim; k0 += 32) {
    gload_lds16(A + (size_t)(brow + row0) * Kdim + k0 + kc0, &As[c0 * 8]);
    gload_lds16(A + (size_t)(brow + row1) * Kdim + k0 + kc1, &As[c1 * 8]);
    gload_lds16(Bt + (size_t)(bcol + row0) * Kdim + k0 + kc0, &Bs[c0 * 8]);
    gload_lds16(Bt + (size_t)(bcol + row1) * Kdim + k0 + kc1, &Bs[c1 * 8]);
    __syncthreads();
    bf16x8 af[4], bfr[4];
    #pragma unroll
    for (int mi = 0; mi < 4; ++mi)
      af[mi] = *(const bf16x8*)&As[(wr + mi * 16 + lr) * 32 + lg * 8];
    #pragma unroll
    for (int ni = 0; ni < 4; ++ni)
      bfr[ni] = *(const bf16x8*)&Bs[(wc + ni * 16 + lr) * 32 + lg * 8];
    #pragma unroll
    for (int mi = 0; mi < 4; ++mi)
      #pragma unroll
      for (int ni = 0; ni < 4; ++ni)
        acc[mi][ni] = __builtin_amdgcn_mfma_f32_16x16x32_bf16(af[mi], bfr[ni], acc[mi][ni], 0, 0, 0);
    __syncthreads();
  }

  if (OUT_MODE == 0) {
    const int mat = bcol >> 10;  // 0:Q 1:K 2:V (block-uniform, 1024 % 128 == 0)
    bf16* outm = (mat == 0) ? q_out : ((mat == 1) ? k_out : v_out);
    const int cb = (bcol & 1023) + wc;
    #pragma unroll
    for (int mi = 0; mi < 4; ++mi)
      #pragma unroll
      for (int ni = 0; ni < 4; ++ni)
        #pragma unroll
        for (int r = 0; r < 4; ++r) {
          const int m = brow + wr + mi * 16 + lg * 4 + r;
          const int c = cb + ni * 16 + lr;
          const int bb = m >> 11, n = m & 2047, hh = c >> 6, dh = c & 63;
          size_t addr;
          if (mat < 2) addr = ((size_t)((bb * NHEADS + hh) * SEQ + n)) * HDIM + dh;
          else         addr = ((size_t)((bb * NHEADS + hh) * HDIM + dh)) * SEQ + n;
          outm[addr] = __float2bfloat16(acc[mi][ni][r]);
        }
  } else {
    #pragma unroll
    for (int mi = 0; mi < 4; ++mi)
      #pragma unroll
      for (int ni = 0; ni < 4; ++ni)
        #pragma unroll
        for (int r = 0; r < 4; ++r) {
          const int m = brow + wr + mi * 16 + lg * 4 + r;
          const int c = bcol + wc + ni * 16 + lr;
          f_out[(size_t)m * Ndim + c] = acc[mi][ni][r] + bias[c];
        }
  }
}

// ---------- causal flash attention ----------
// Qh,Kh: [B][H][N][64] bf16; Vt: [B][H][64][N] bf16; Ctx: [M][1024] bf16
__global__ __launch_bounds__(256) void attn_kernel(const bf16* __restrict__ Qh,
                                                   const bf16* __restrict__ Kh,
                                                   const bf16* __restrict__ Vt,
                                                   bf16* __restrict__ Ctx) {
  __shared__ __align__(16) bf16 Plds[4][32][128];
  const int tid = threadIdx.x, lane = tid & 63, wave = tid >> 6;
  const int lr = lane & 15, lg = lane >> 4;
  const int bid = blockIdx.x;
  const int qb = bid & 15;          // 16 q-tiles of 128
  const int h = (bid >> 4) & 15;
  const int bb = bid >> 8;
  const size_t headQK = (size_t)(bb * NHEADS + h) * SEQ * HDIM;
  const int q0 = qb * 128 + wave * 32;

  // Q fragments, held for the whole block
  bf16x8 qf[2][2];
  #pragma unroll
  for (int mi = 0; mi < 2; ++mi)
    #pragma unroll
    for (int ks = 0; ks < 2; ++ks)
      qf[mi][ks] = *(const bf16x8*)&Qh[headQK + (size_t)(q0 + mi * 16 + lr) * HDIM + ks * 32 + lg * 8];

  f32x4 oacc[2][4] = {};
  float mrow[2][4], lrow[2][4];
  #pragma unroll
  for (int mi = 0; mi < 2; ++mi)
    #pragma unroll
    for (int r = 0; r < 4; ++r) { mrow[mi][r] = -1e30f; lrow[mi][r] = 0.f; }

  const int ntiles = qb + 1;
  for (int t = 0; t < ntiles; ++t) {
    const int k0 = t * 128;
    // ---- S = Q K^T (per wave: 32 x 128) ----
    f32x4 sacc[2][8] = {};
    #pragma unroll
    for (int ni = 0; ni < 8; ++ni)
      #pragma unroll
      for (int ks = 0; ks < 2; ++ks) {
        const bf16x8 kf =
            *(const bf16x8*)&Kh[headQK + (size_t)(k0 + ni * 16 + lr) * HDIM + ks * 32 + lg * 8];
        #pragma unroll
        for (int mi = 0; mi < 2; ++mi)
          sacc[mi][ni] = __builtin_amdgcn_mfma_f32_16x16x32_bf16(qf[mi][ks], kf, sacc[mi][ni], 0, 0, 0);
      }
    // ---- scale, causal mask, online softmax ----
    const bool diag = (t == qb);
    #pragma unroll
    for (int mi = 0; mi < 2; ++mi)
      #pragma unroll
      for (int r = 0; r < 4; ++r) {
        float mx = -1e30f;
        #pragma unroll
        for (int ni = 0; ni < 8; ++ni) {
          float s = sacc[mi][ni][r] * 0.125f;
          if (diag) {
            const int qrow = q0 + mi * 16 + lg * 4 + r;
            const int kcol = k0 + ni * 16 + lr;
            if (kcol > qrow) s = -1e30f;
          }
          sacc[mi][ni][r] = s;
          mx = fmaxf(mx, s);
        }
        #pragma unroll
        for (int off = 1; off < 16; off <<= 1) mx = fmaxf(mx, __shfl_xor(mx, off, 64));
        const float mnew = fmaxf(mrow[mi][r], mx);
        const float sc = __expf(mrow[mi][r] - mnew);
        mrow[mi][r] = mnew;
        float rs = 0.f;
        #pragma unroll
        for (int ni = 0; ni < 8; ++ni) {
          const float p = __expf(sacc[mi][ni][r] - mnew);
          sacc[mi][ni][r] = p;
          rs += p;
        }
        #pragma unroll
        for (int off = 1; off < 16; off <<= 1) rs += __shfl_xor(rs, off, 64);
        lrow[mi][r] = lrow[mi][r] * sc + rs;
        #pragma unroll
        for (int nj = 0; nj < 4; ++nj) oacc[mi][nj][r] *= sc;
      }
    // ---- P -> LDS (re-fragment for PV A-operand) ----
    __syncthreads();
    #pragma unroll
    for (int mi = 0; mi < 2; ++mi)
      #pragma unroll
      for (int ni = 0; ni < 8; ++ni)
        #pragma unroll
        for (int r = 0; r < 4; ++r)
          Plds[wave][mi * 16 + lg * 4 + r][ni * 16 + lr] = __float2bfloat16(sacc[mi][ni][r]);
    __syncthreads();
    bf16x8 pa[2][4];
    #pragma unroll
    for (int mi = 0; mi < 2; ++mi)
      #pragma unroll
      for (int ks = 0; ks < 4; ++ks)
        pa[mi][ks] = *(const bf16x8*)&Plds[wave][mi * 16 + lr][ks * 32 + lg * 8];
    // ---- O += P V ----
    #pragma unroll
    for (int nj = 0; nj < 4; ++nj)
      #pragma unroll
      for (int ks = 0; ks < 4; ++ks) {
        const bf16x8 vf =
            *(const bf16x8*)&Vt[headQK + (size_t)(nj * 16 + lr) * SEQ + k0 + ks * 32 + lg * 8];
        #pragma unroll
        for (int mi = 0; mi < 2; ++mi)
          oacc[mi][nj] = __builtin_amdgcn_mfma_f32_16x16x32_bf16(pa[mi][ks], vf, oacc[mi][nj], 0, 0, 0);
      }
  }
  // ---- write ctx (merge heads) ----
  #pragma unroll
  for (int mi = 0; mi < 2; ++mi)
    #pragma unroll
    for (int nj = 0; nj < 4; ++nj)
      #pragma unroll
      for (int r = 0; r < 4; ++r) {
        const int m = bb * SEQ + q0 + mi * 16 + lg * 4 + r;
        const int c = h * HDIM + nj * 16 + lr;
        Ctx[(size_t)m * DMODEL + c] = __float2bfloat16(oacc[mi][nj][r] / lrow[mi][r]);
      }
}

extern "C" void kernel_launch(void* const* d_in, const int* in_sizes, int n_in,
                              void* d_out, int out_size, void* d_ws, size_t ws_size,
                              hipStream_t stream) {
  const float* X  = (const float*)d_in[0];
  const float* Wq = (const float*)d_in[1];
  const float* Wk = (const float*)d_in[2];
  const float* Wv = (const float*)d_in[3];
  const float* Wo = (const float*)d_in[4];
  const float* bo = (const float*)d_in[5];
  float* out = (float*)d_out;

  char* p = (char*)d_ws;
  bf16* Xb   = (bf16*)p; p += (size_t)MROWS * DMODEL * 2;       // 8 MB
  bf16* Wqkv = (bf16*)p; p += (size_t)3 * DMODEL * DMODEL * 2;  // 6 MB  [3072][1024]
  bf16* Wot  = (bf16*)p; p += (size_t)DMODEL * DMODEL * 2;      // 2 MB
  bf16* Qh   = (bf16*)p; p += (size_t)MROWS * DMODEL * 2;       // 8 MB
  bf16* Kh   = (bf16*)p; p += (size_t)MROWS * DMODEL * 2;       // 8 MB
  bf16* Vt   = (bf16*)p; p += (size_t)MROWS * DMODEL * 2;       // 8 MB
  bf16* Ctx  = (bf16*)p; p += (size_t)MROWS * DMODEL * 2;       // 8 MB

  cast_x_kernel<<<(MROWS * DMODEL) / 1024, 256, 0, stream>>>(X, Xb);
  dim3 tg(32, 32);
  wtrans_kernel<<<tg, 256, 0, stream>>>(Wq, Wqkv);
  wtrans_kernel<<<tg, 256, 0, stream>>>(Wk, Wqkv + (size_t)DMODEL * DMODEL);
  wtrans_kernel<<<tg, 256, 0, stream>>>(Wv, Wqkv + (size_t)2 * DMODEL * DMODEL);
  wtrans_kernel<<<tg, 256, 0, stream>>>(Wo, Wot);

  dim3 g1(3072 / 128, MROWS / 128);  // 24 x 32
  gemm_bt<0><<<g1, 256, 0, stream>>>(Xb, Wqkv, DMODEL, Qh, Kh, Vt, nullptr, nullptr, 3072);

  attn_kernel<<<BATCH * NHEADS * (SEQ / 128), 256, 0, stream>>>(Qh, Kh, Vt, Ctx);

  dim3 g2(DMODEL / 128, MROWS / 128);  // 8 x 32
  gemm_bt<1><<<g2, 256, 0, stream>>>(Ctx, Wot, DMODEL, nullptr, nullptr, nullptr, out, bo, DMODEL);
}

// Round 2
// 278.968 us; speedup vs baseline: 1.0520x; 1.0520x over previous
//
#include <hip/hip_runtime.h>
#include <hip/hip_bf16.h>
#include <cstdint>

#define NHEADS 16
#define HDIM   64
#define BATCH  2
#define SEQ    2048
#define DMODEL 1024
#define MROWS  (BATCH * SEQ)   // 4096

using bf16 = __hip_bfloat16;
typedef __attribute__((ext_vector_type(8))) short bf16x8;
typedef __attribute__((ext_vector_type(4))) short bf16x4;
typedef __attribute__((ext_vector_type(4))) float f32x4;

// 0.125 (1/sqrt(64)) * log2(e): softmax in exp2 domain
#define C_SCALE 0.1803368801111f

__device__ __forceinline__ void gload_lds16(const bf16* g, bf16* l) {
  __builtin_amdgcn_global_load_lds(
      (const __attribute__((address_space(1))) unsigned int*)g,
      (__attribute__((address_space(3))) unsigned int*)l, 16, 0, 0);
}

__device__ __forceinline__ short bf16bits(float x) {
  __hip_bfloat16 h = __float2bfloat16(x);
  return *reinterpret_cast<short*>(&h);
}

// ---------- cast X fp32 -> bf16 ----------
__global__ __launch_bounds__(256) void cast_x_kernel(const float* __restrict__ in,
                                                     bf16* __restrict__ out) {
  const int i = (blockIdx.x * 256 + threadIdx.x) * 4;
  const float4 v = *reinterpret_cast<const float4*>(in + i);
  __hip_bfloat162 p0 = __float22bfloat162_rn(make_float2(v.x, v.y));
  __hip_bfloat162 p1 = __float22bfloat162_rn(make_float2(v.z, v.w));
  reinterpret_cast<__hip_bfloat162*>(out + i)[0] = p0;
  reinterpret_cast<__hip_bfloat162*>(out + i)[1] = p1;
}

// ---------- transpose-cast W [K][N] fp32 -> Wt [N][K] bf16 (3 mats via z) ----------
__global__ __launch_bounds__(256) void wtrans_kernel(const float* __restrict__ W0,
                                                     const float* __restrict__ W1,
                                                     const float* __restrict__ W2,
                                                     bf16* __restrict__ Wt) {
  __shared__ float tile[32][33];
  const float* W = (blockIdx.z == 0) ? W0 : ((blockIdx.z == 1) ? W1 : W2);
  bf16* out = Wt + (size_t)blockIdx.z * DMODEL * DMODEL;
  const int n0 = blockIdx.x * 32, k0 = blockIdx.y * 32;
  const int tx = threadIdx.x & 31, ty = threadIdx.x >> 5;  // 32 x 8
  #pragma unroll
  for (int r = 0; r < 32; r += 8)
    tile[ty + r][tx] = W[(size_t)(k0 + ty + r) * DMODEL + n0 + tx];
  __syncthreads();
  #pragma unroll
  for (int r = 0; r < 32; r += 8)
    out[(size_t)(n0 + ty + r) * DMODEL + k0 + tx] = __float2bfloat16(tile[tx][ty + r]);
}

// ---------- GEMM: C[M][N] = A[M][K] * Bt[N][K]^T ----------
template <int OUT_MODE>
__global__ __launch_bounds__(256) void gemm_bt(const bf16* __restrict__ A,
                                               const bf16* __restrict__ Bt, int Kdim,
                                               bf16* __restrict__ q_out, bf16* __restrict__ k_out,
                                               bf16* __restrict__ v_out,
                                               float* __restrict__ f_out,
                                               const float* __restrict__ bias, int Ndim) {
  __shared__ __align__(16) bf16 As[128 * 32];
  __shared__ __align__(16) bf16 Bs[128 * 32];
  const int tid = threadIdx.x;
  const int lane = tid & 63, wave = tid >> 6;
  const int lr = lane & 15, lg = lane >> 4;
  const int brow = blockIdx.y * 128, bcol = blockIdx.x * 128;
  const int wr = (wave >> 1) * 64, wc = (wave & 1) * 64;
  f32x4 acc[4][4] = {};

  const int c0 = tid, c1 = 256 + tid;
  const int row0 = c0 >> 2, kc0 = (c0 & 3) * 8;
  const int row1 = c1 >> 2, kc1 = (c1 & 3) * 8;

  for (int k0 = 0; k0 < Kdim; k0 += 32) {
    gload_lds16(A + (size_t)(brow + row0) * Kdim + k0 + kc0, &As[c0 * 8]);
    gload_lds16(A + (size_t)(brow + row1) * Kdim + k0 + kc1, &As[c1 * 8]);
    gload_lds16(Bt + (size_t)(bcol + row0) * Kdim + k0 + kc0, &Bs[c0 * 8]);
    gload_lds16(Bt + (size_t)(bcol + row1) * Kdim + k0 + kc1, &Bs[c1 * 8]);
    __syncthreads();
    bf16x8 af[4], bfr[4];
    #pragma unroll
    for (int mi = 0; mi < 4; ++mi)
      af[mi] = *(const bf16x8*)&As[(wr + mi * 16 + lr) * 32 + lg * 8];
    #pragma unroll
    for (int ni = 0; ni < 4; ++ni)
      bfr[ni] = *(const bf16x8*)&Bs[(wc + ni * 16 + lr) * 32 + lg * 8];
    #pragma unroll
    for (int mi = 0; mi < 4; ++mi)
      #pragma unroll
      for (int ni = 0; ni < 4; ++ni)
        acc[mi][ni] = __builtin_amdgcn_mfma_f32_16x16x32_bf16(af[mi], bfr[ni], acc[mi][ni], 0, 0, 0);
    __syncthreads();
  }

  if (OUT_MODE == 0) {
    const int mat = bcol >> 10;  // 0:Q 1:K 2:V (block-uniform, 1024 % 128 == 0)
    bf16* outm = (mat == 0) ? q_out : ((mat == 1) ? k_out : v_out);
    const int cb = (bcol & 1023) + wc;
    #pragma unroll
    for (int mi = 0; mi < 4; ++mi)
      #pragma unroll
      for (int ni = 0; ni < 4; ++ni)
        #pragma unroll
        for (int r = 0; r < 4; ++r) {
          const int m = brow + wr + mi * 16 + lg * 4 + r;
          const int c = cb + ni * 16 + lr;
          const int bb = m >> 11, n = m & 2047, hh = c >> 6, dh = c & 63;
          size_t addr;
          if (mat < 2) addr = ((size_t)((bb * NHEADS + hh) * SEQ + n)) * HDIM + dh;
          else         addr = ((size_t)((bb * NHEADS + hh) * HDIM + dh)) * SEQ + n;
          outm[addr] = __float2bfloat16(acc[mi][ni][r]);
        }
  } else {
    #pragma unroll
    for (int mi = 0; mi < 4; ++mi)
      #pragma unroll
      for (int ni = 0; ni < 4; ++ni)
        #pragma unroll
        for (int r = 0; r < 4; ++r) {
          const int m = brow + wr + mi * 16 + lg * 4 + r;
          const int c = bcol + wc + ni * 16 + lr;
          f_out[(size_t)m * Ndim + c] = acc[mi][ni][r] + bias[c];
        }
  }
}

// ---------- causal flash attention (swapped-QK^T, LDS-free, balanced) ----------
// One wave owns a 16-row q-tile; S^T = mfma(K,Q) so each lane holds one q-row's
// P values (q = lane&15, key = ni*16 + lg*4 + r). PV uses mfma 16x16x16 whose
// B-fragment layout matches S^T's C-layout exactly -> no cross-lane movement.
template <bool TAIL>
__device__ __forceinline__ void attn_tile(const bf16* __restrict__ Kp,
                                          const bf16* __restrict__ Vp,
                                          int k0, int nlim, int qg, int lr, int lg,
                                          const bf16x8 qf[2], f32x4 oacc[4],
                                          float& m, float& l) {
  f32x4 sacc[8];
  #pragma unroll 8
  for (int ni = 0; ni < nlim; ++ni) {
    const bf16x8 kf0 = *(const bf16x8*)&Kp[(size_t)(k0 + ni * 16 + lr) * HDIM + lg * 8];
    const bf16x8 kf1 = *(const bf16x8*)&Kp[(size_t)(k0 + ni * 16 + lr) * HDIM + 32 + lg * 8];
    f32x4 s = {};
    s = __builtin_amdgcn_mfma_f32_16x16x32_bf16(kf0, qf[0], s, 0, 0, 0);
    s = __builtin_amdgcn_mfma_f32_16x16x32_bf16(kf1, qf[1], s, 0, 0, 0);
    sacc[ni] = s;
  }
  // scale (+mask) + row max (row lives in-lane + across lg groups)
  float mx = -1e30f;
  #pragma unroll 8
  for (int ni = 0; ni < nlim; ++ni)
    #pragma unroll
    for (int r = 0; r < 4; ++r) {
      float v = sacc[ni][r] * C_SCALE;
      if (TAIL) {
        const int key = k0 + ni * 16 + lg * 4 + r;
        if (key > qg) v = -1e30f;
      }
      sacc[ni][r] = v;
      mx = fmaxf(mx, v);
    }
  mx = fmaxf(mx, __shfl_xor(mx, 16, 64));
  mx = fmaxf(mx, __shfl_xor(mx, 32, 64));
  const float mnew = fmaxf(m, mx);
  const float sc = __builtin_amdgcn_exp2f(m - mnew);
  m = mnew;
  float rs = 0.f;
  bf16x4 pb[8];
  #pragma unroll 8
  for (int ni = 0; ni < nlim; ++ni)
    #pragma unroll
    for (int r = 0; r < 4; ++r) {
      const float p = __builtin_amdgcn_exp2f(sacc[ni][r] - mnew);
      rs += p;
      pb[ni][r] = bf16bits(p);
    }
  rs += __shfl_xor(rs, 16, 64);
  rs += __shfl_xor(rs, 32, 64);
  l = l * sc + rs;
  #pragma unroll
  for (int nj = 0; nj < 4; ++nj)
    #pragma unroll
    for (int r = 0; r < 4; ++r) oacc[nj][r] *= sc;
  // O^T += V^T P^T : A = Vt fragment (contiguous 8B), B = pb (in-register)
  #pragma unroll 8
  for (int ni = 0; ni < nlim; ++ni)
    #pragma unroll
    for (int nj = 0; nj < 4; ++nj) {
      const bf16x4 vf = *(const bf16x4*)&Vp[(size_t)(nj * 16 + lr) * SEQ + k0 + ni * 16 + lg * 4];
      oacc[nj] = __builtin_amdgcn_mfma_f32_16x16x16bf16_1k(vf, pb[ni], oacc[nj], 0, 0, 0);
    }
}

__global__ __launch_bounds__(256) void attn_kernel(const bf16* __restrict__ Qh,
                                                   const bf16* __restrict__ Kh,
                                                   const bf16* __restrict__ Vt,
                                                   bf16* __restrict__ Ctx) {
  const int tid = threadIdx.x, lane = tid & 63, wave = tid >> 6;
  const int lr = lane & 15, lg = lane >> 4;
  const int w = blockIdx.x * 4 + wave;   // 0..2047, fully independent waves
  const int bh = w >> 6;                 // 32 (batch,head) groups
  const int pid = w & 63;                // pair id: tasks (pid, 127-pid), work == 17 tiles
  const int b = bh >> 4, h = bh & 15;
  const size_t headoff = (size_t)bh * SEQ * HDIM;
  const bf16* Qp = Qh + headoff;
  const bf16* Kp = Kh + headoff;
  const bf16* Vp = Vt + headoff;

  #pragma unroll
  for (int task = 0; task < 2; ++task) {
    const int ti = task ? (127 - pid) : pid;
    const int q0 = ti * 16;
    const int qg = q0 + lr;
    bf16x8 qf[2];
    #pragma unroll
    for (int ks = 0; ks < 2; ++ks)
      qf[ks] = *(const bf16x8*)&Qp[(size_t)(q0 + lr) * HDIM + ks * 32 + lg * 8];
    f32x4 oacc[4] = {};
    float m = -1e30f, l = 0.f;
    const int T = q0 >> 7;
    for (int t = 0; t < T; ++t)
      attn_tile<false>(Kp, Vp, t * 128, 8, qg, lr, lg, qf, oacc, m, l);
    const int nlim = ((q0 + 15 - T * 128) >> 4) + 1;
    attn_tile<true>(Kp, Vp, T * 128, nlim, qg, lr, lg, qf, oacc, m, l);

    const float rl = 1.0f / l;
    const int mrow = b * SEQ + q0 + lr;
    #pragma unroll
    for (int nj = 0; nj < 4; ++nj) {
      ushort4 o;
      o.x = (unsigned short)bf16bits(oacc[nj][0] * rl);
      o.y = (unsigned short)bf16bits(oacc[nj][1] * rl);
      o.z = (unsigned short)bf16bits(oacc[nj][2] * rl);
      o.w = (unsigned short)bf16bits(oacc[nj][3] * rl);
      *reinterpret_cast<ushort4*>(&Ctx[(size_t)mrow * DMODEL + h * HDIM + nj * 16 + lg * 4]) = o;
    }
  }
}

extern "C" void kernel_launch(void* const* d_in, const int* in_sizes, int n_in,
                              void* d_out, int out_size, void* d_ws, size_t ws_size,
                              hipStream_t stream) {
  const float* X  = (const float*)d_in[0];
  const float* Wq = (const float*)d_in[1];
  const float* Wk = (const float*)d_in[2];
  const float* Wv = (const float*)d_in[3];
  const float* Wo = (const float*)d_in[4];
  const float* bo = (const float*)d_in[5];
  float* out = (float*)d_out;

  char* p = (char*)d_ws;
  bf16* Xb   = (bf16*)p; p += (size_t)MROWS * DMODEL * 2;       // 8 MB
  bf16* Wqkv = (bf16*)p; p += (size_t)3 * DMODEL * DMODEL * 2;  // 6 MB  [3072][1024]
  bf16* Wot  = (bf16*)p; p += (size_t)DMODEL * DMODEL * 2;      // 2 MB
  bf16* Qh   = (bf16*)p; p += (size_t)MROWS * DMODEL * 2;       // 8 MB
  bf16* Kh   = (bf16*)p; p += (size_t)MROWS * DMODEL * 2;       // 8 MB
  bf16* Vt   = (bf16*)p; p += (size_t)MROWS * DMODEL * 2;       // 8 MB
  bf16* Ctx  = (bf16*)p; p += (size_t)MROWS * DMODEL * 2;       // 8 MB

  cast_x_kernel<<<(MROWS * DMODEL) / 1024, 256, 0, stream>>>(X, Xb);
  dim3 tg(32, 32, 3);
  wtrans_kernel<<<tg, 256, 0, stream>>>(Wq, Wk, Wv, Wqkv);
  dim3 tg1(32, 32, 1);
  wtrans_kernel<<<tg1, 256, 0, stream>>>(Wo, Wo, Wo, Wot);

  dim3 g1(3072 / 128, MROWS / 128);  // 24 x 32
  gemm_bt<0><<<g1, 256, 0, stream>>>(Xb, Wqkv, DMODEL, Qh, Kh, Vt, nullptr, nullptr, 3072);

  attn_kernel<<<512, 256, 0, stream>>>(Qh, Kh, Vt, Ctx);

  dim3 g2(DMODEL / 128, MROWS / 128);  // 8 x 32
  gemm_bt<1><<<g2, 256, 0, stream>>>(Ctx, Wot, DMODEL, nullptr, nullptr, nullptr, out, bo, DMODEL);
}